// Round 8
// baseline (664.699 us; speedup 1.0000x reference)
//
#include <hip/hip_runtime.h>
#include <stdint.h>

#define NPIX 1024
#define NEDGE 1984
#define NSORT 2048
#define CROWS 64          // replay label rows (4 waves x 16)
#define CNTW (NPIX + 2)   // pad rows: replay lanes hit distinct banks

// ---- d_ws layout (~1.05 MB) ----
#define WS_PART   0u          // f64[256]   per-task loss partials
#define WS_SKIP   2048u       // u32[64]    per-window skip flag
#define WS_NLAB   2304u       // u32[128]   per (bat,win) active-label count
#define WS_PW     4096u       // f32[128*1024]
#define WS_LAB    528384u     // u16[128*1024]  CC labels (min-pixel-id+1, 0=bg)
#define WS_LABD   790528u     // u16[128*1024]  active dense id+1 at min pixel

__device__ __forceinline__ void edge_nodes(int e, int& a, int& b) {
  if (e < 992) { int r = e / 31; int c = e - r * 31; a = (r << 5) + c; b = a + 1; }
  else         { a = e - 992; b = a + 32; }
}

// ============ K1: load + skip predicate + 8-conn CC + label census ============
__global__ __launch_bounds__(256) void k1_prep(const float* __restrict__ y_true,
                                               const float* __restrict__ y_pred,
                                               char* __restrict__ ws) {
  __shared__ float    Pw[NPIX];
  __shared__ uint16_t lab[NPIX];
  __shared__ uint8_t  maskv[NPIX];
  __shared__ uint32_t lcnt[NPIX];
  __shared__ unsigned minP, maxP, minT, maxT;
  __shared__ int nl, changed;
  const int tid = threadIdx.x, pw = blockIdx.x, bat = pw >> 6, win = pw & 63;
  const int wr = win >> 3, wc = win & 7;
  if (tid == 0) { minP = ~0u; maxP = 0u; minT = ~0u; maxT = 0u; nl = 0; }
  __syncthreads();
  {
    unsigned mnP = ~0u, mxP = 0u, mnT = ~0u, mxT = 0u;
    for (int i = tid; i < 2 * NPIX; i += 256) {
      int bb = i >> 10, p = i & (NPIX - 1);
      int r = p >> 5, c = p & 31;
      size_t g = ((size_t)(bb * 256 + wr * 32 + r)) * 256 + (size_t)(wc * 32 + c);
      float pv = y_pred[g], tv = y_true[g];
      unsigned pu = __float_as_uint(pv), tu = __float_as_uint(tv);
      mnP = min(mnP, pu); mxP = max(mxP, pu);
      mnT = min(mnT, tu); mxT = max(mxT, tu);
      if (bb == bat) {
        Pw[p] = pv; maskv[p] = (tv == 0.f) ? 1 : 0;
        lab[p] = (tv == 0.f) ? (uint16_t)(p + 1) : (uint16_t)0;
        lcnt[p] = 0u;
      }
    }
    atomicMin(&minP, mnP); atomicMax(&maxP, mxP);   // valid: values >= 0
    atomicMin(&minT, mnT); atomicMax(&maxT, mxT);
  }
  __syncthreads();
  {
    float a = __uint_as_float(minP), b = __uint_as_float(maxP);
    float c2 = __uint_as_float(minT), d = __uint_as_float(maxT);
    int skip = (a == 1.f || b == 0.f || c2 == 1.f || d == 0.f) ? 1 : 0;
    if (tid == 0) ((uint32_t*)(ws + WS_SKIP))[win] = (uint32_t)skip;  // dup write: same value
    if (skip) return;
  }
  for (;;) {
    if (tid == 0) changed = 0;
    __syncthreads();
    for (int p = tid; p < NPIX; p += 256) {
      if (!maskv[p]) continue;
      int r = p >> 5, c = p & 31;
      unsigned m = lab[p];
      bool up = r > 0, dn = r < 31, lf = c > 0, rt = c < 31;
      if (up) {
        if (maskv[p-32])       { unsigned v = lab[p-32]; if (v < m) m = v; }
        if (lf && maskv[p-33]) { unsigned v = lab[p-33]; if (v < m) m = v; }
        if (rt && maskv[p-31]) { unsigned v = lab[p-31]; if (v < m) m = v; }
      }
      if (dn) {
        if (maskv[p+32])       { unsigned v = lab[p+32]; if (v < m) m = v; }
        if (lf && maskv[p+31]) { unsigned v = lab[p+31]; if (v < m) m = v; }
        if (rt && maskv[p+33]) { unsigned v = lab[p+33]; if (v < m) m = v; }
      }
      if (lf && maskv[p-1]) { unsigned v = lab[p-1]; if (v < m) m = v; }
      if (rt && maskv[p+1]) { unsigned v = lab[p+1]; if (v < m) m = v; }
      unsigned m2 = lab[m - 1]; if (m2 && m2 < m) m = m2;
      m2 = lab[m - 1];          if (m2 && m2 < m) m = m2;
      if (m < (unsigned)lab[p]) { lab[p] = (uint16_t)m; changed = 1; }
    }
    __syncthreads();
    int ch = changed;
    __syncthreads();
    if (!ch) break;
  }
  for (int p = tid; p < NPIX; p += 256)
    if (maskv[p]) atomicAdd(&lcnt[lab[p] - 1], 1u);
  __syncthreads();
  uint16_t* labDG = (uint16_t*)(ws + WS_LABD) + (size_t)pw * NPIX;
  for (int p = tid; p < NPIX; p += 256) {
    uint16_t v = 0;
    if (maskv[p] && lab[p] == (uint16_t)(p + 1) && lcnt[p] >= 2u)
      v = (uint16_t)(atomicAdd(&nl, 1) + 1);
    labDG[p] = v;
  }
  __syncthreads();
  float*    PwG  = (float*)(ws + WS_PW)  + (size_t)pw * NPIX;
  uint16_t* labG = (uint16_t*)(ws + WS_LAB) + (size_t)pw * NPIX;
  for (int p = tid; p < NPIX; p += 256) { PwG[p] = Pw[p]; labG[p] = lab[p]; }
  if (tid == 0) ((uint32_t*)(ws + WS_NLAB))[pw] = (uint32_t)nl;
}

// ============ K2: fused sort + Kruskal + replay + epilogue (one task/block) ============
__global__ __launch_bounds__(256) void k2_fused(char* __restrict__ ws) {
  __shared__ union {
    struct {
      unsigned long long keys[NSORT];   // 16384 B (sort + kruskal edge order)
      uint16_t par[NPIX];               //  2048 B
      uint16_t tot[NPIX];               //  2048 B
    } kp;
    uint16_t cnt[CROWS][CNTW];          // 131328 B (replay)
    double   red[256];                  //   2048 B (final reduction)
  } u;                                  // union = 131328 B
  __shared__ float    Pw[NPIX];
  __shared__ uint16_t lab[NPIX];
  __shared__ uint16_t labD[NPIX];
  __shared__ uint32_t recW[NPIX];
  __shared__ uint32_t totp[NPIX];
  __shared__ uint32_t same[NPIX];
  __shared__ unsigned Ssum;
  __shared__ int Msh;
  const int tid = threadIdx.x, t = blockIdx.x;
  const int sign = t & 1, win = (t >> 1) & 63, bat = t >> 7;
  const int pw = bat * 64 + win;
  double* partG = (double*)(ws + WS_PART);
  if (((const uint32_t*)(ws + WS_SKIP))[win]) { if (tid == 0) partG[t] = 0.0; return; }
  const int nlab = (int)((const uint32_t*)(ws + WS_NLAB))[pw];
  if (tid == 0) { Ssum = 0u; Msh = 0; }
  {
    const float*    PwG   = (const float*)(ws + WS_PW)   + (size_t)pw * NPIX;
    const uint16_t* labG  = (const uint16_t*)(ws + WS_LAB)  + (size_t)pw * NPIX;
    const uint16_t* labDG = (const uint16_t*)(ws + WS_LABD) + (size_t)pw * NPIX;
    for (int p = tid; p < NPIX; p += 256) {
      Pw[p] = PwG[p]; lab[p] = labG[p]; labD[p] = labDG[p];
      u.kp.par[p] = (uint16_t)p; u.kp.tot[p] = lab[p] ? 1 : 0;
      same[p] = 0u;
    }
  }
  __syncthreads();
  // ---- edge keys (cost desc, index asc -> pack (~bits(cost), e), sort asc)
  for (int e = tid; e < NSORT; e += 256) {
    if (e < NEDGE) {
      int a, b; edge_nodes(e, a, b);
      int cls = (lab[a] ? 0 : 1) + (lab[b] ? 0 : 1);
      float cost = Pw[a] + Pw[b];
      if (sign == 0) { if (cls == 2) cost = 20.0f; }   // costs_n[gt>20]=20
      else           { if (cls == 0) cost = 0.0f;  }   // costs_p[gt<10]=0
      u.kp.keys[e] = (((unsigned long long)(__float_as_uint(cost) ^ 0xFFFFFFFFu)) << 32)
                     | (unsigned long long)(unsigned)e;
    } else u.kp.keys[e] = ~0ull;
  }
  __syncthreads();
  // ---- register-fused bitonic sort (R7-proven)
  {
    unsigned long long x[8];
    const int baseI = tid * 8;
    #pragma unroll
    for (int v = 0; v < 8; ++v) x[v] = u.kp.keys[baseI + v];
    #pragma unroll
    for (int kk = 2; kk <= 8; kk <<= 1) {
      #pragma unroll
      for (int j = kk >> 1; j > 0; j >>= 1) {
        #pragma unroll
        for (int v = 0; v < 8; ++v) {
          int p = v ^ j;
          if (p > v) {
            bool asc = (((baseI + v) & kk) == 0);
            unsigned long long A = x[v], B = x[p];
            if ((A > B) == asc) { x[v] = B; x[p] = A; }
          }
        }
      }
    }
    #pragma unroll
    for (int v = 0; v < 8; ++v) u.kp.keys[baseI + v] = x[v];
  }
  for (int k = 16; k <= NSORT; k <<= 1) {
    for (int j = k >> 1; j >= 8; j >>= 1) {
      __syncthreads();
      for (int q = tid; q < NSORT / 2; q += 256) {
        int i = ((q & ~(j - 1)) << 1) | (q & (j - 1));
        int p = i + j;
        bool asc = ((i & k) == 0);
        unsigned long long A = u.kp.keys[i], B = u.kp.keys[p];
        if ((A > B) == asc) { u.kp.keys[i] = B; u.kp.keys[p] = A; }
      }
    }
    __syncthreads();
    {
      unsigned long long x[8];
      const int baseI = tid * 8;
      const bool asc = ((baseI & k) == 0);
      #pragma unroll
      for (int v = 0; v < 8; ++v) x[v] = u.kp.keys[baseI + v];
      #pragma unroll
      for (int j = 4; j > 0; j >>= 1) {
        #pragma unroll
        for (int v = 0; v < 8; ++v) {
          int p = v ^ j;
          if (p > v) {
            unsigned long long A = x[v], B = x[p];
            if ((A > B) == asc) { x[v] = B; x[p] = A; }
          }
        }
      }
      #pragma unroll
      for (int v = 0; v < 8; ++v) u.kp.keys[baseI + v] = x[v];
    }
  }
  __syncthreads();
  // ---- wave-cooperative Kruskal (wave 0), branchless lookups; records -> LDS.
  // All ballots/readlanes in uniform control flow (CDNA exec-mask rule).
  if (tid < 64) {
    const int lane = tid;
    int mTotal = 0;
    for (int base = 0; base < NEDGE; base += 64) {     // first NEDGE slots are real edges
      unsigned e = (unsigned)u.kp.keys[base + lane];
      int a, b; edge_nodes((int)e, a, b);
      int xa = a, xb = b;
      for (;;) {
        int pa = u.kp.par[xa], pb = u.kp.par[xb];   // read-only dual walk
        if (pa == xa && pb == xb) break;
        xa = pa; xb = pb;
      }
      int ra = xa, rb = xb;
      unsigned sa = u.kp.tot[ra], sb = u.kp.tot[rb];
      bool cand = (ra != rb);
      unsigned long long cm = __ballot(cand);
      unsigned w0 = (unsigned)ra | ((unsigned)rb << 10) | (e << 20);
      unsigned w1 = sa | (sb << 11);

      int mb = 0;
      int mFrom = -1, mTo = -1; unsigned szTo = 0;
      while (cm) {
        int i = __ffsll((long long)cm) - 1;
        cm &= cm - 1;
        unsigned W0 = (unsigned)__builtin_amdgcn_readlane((int)w0, i);
        unsigned W1 = (unsigned)__builtin_amdgcn_readlane((int)w1, i);
        int rA = (int)(W0 & 1023u);
        int rB = (int)((W0 >> 10) & 1023u);
        unsigned eI = W0 >> 20;
        unsigned sA = W1 & 2047u;
        unsigned sB = W1 >> 11;
        {  // O(1) rename (always-current mTo invariant), branchless
          unsigned long long mmA = __ballot(mFrom == rA);
          unsigned long long mmB = __ballot(mFrom == rB);
          int idxA = (__ffsll((long long)mmA) - 1) & 63;
          int idxB = (__ffsll((long long)mmB) - 1) & 63;
          int vA = __builtin_amdgcn_readlane(mTo, idxA);
          int vB = __builtin_amdgcn_readlane(mTo, idxB);
          rA = mmA ? vA : rA;
          rB = mmB ? vB : rB;
        }
        if (rA == rB) continue;
        {  // current sizes: highest slot with mTo==r, branchless
          unsigned long long ma = __ballot(mTo == rA);
          unsigned long long mc = __ballot(mTo == rB);
          int idxA = 63 - __clzll((long long)(ma | 1));
          int idxC = 63 - __clzll((long long)(mc | 1));
          unsigned vA = (unsigned)__builtin_amdgcn_readlane((int)szTo, idxA);
          unsigned vC = (unsigned)__builtin_amdgcn_readlane((int)szTo, idxC);
          sA = ma ? vA : sA;
          sB = mc ? vC : sB;
        }
        if (lane == mb) { mFrom = rB; mTo = rA; szTo = sA + sB; }
        if (mTo == rB) mTo = rA;            // maintain invariant
        ++mb;
        if (lane == 0) {
          u.kp.par[rB] = (uint16_t)rA;      // reference orientation
          u.kp.tot[rA] = (uint16_t)(sA + sB);
          if (sB > 0) {
            recW[mTotal] = eI | ((unsigned)rA << 11) | ((unsigned)rB << 21);
            totp[mTotal] = sA * sB;
          }
        }
        if (sB > 0) ++mTotal;               // uniform
      }
      // batched pointer-jump compression (1 write/node, conflict-free)
      if (mb && (base + 64 < NEDGE)) {
        for (int pass = 0; pass < 2; ++pass) {
          uint16_t vv[16];
          #pragma unroll
          for (int j = 0; j < 16; ++j) vv[j] = u.kp.par[j * 64 + lane];
          #pragma unroll
          for (int j = 0; j < 16; ++j) vv[j] = u.kp.par[vv[j]];
          #pragma unroll
          for (int j = 0; j < 16; ++j) u.kp.par[j * 64 + lane] = vv[j];
        }
      }
    }
    if (lane == 0) Msh = mTotal;
  }
  __syncthreads();
  const int M = Msh;

  // ---- replay: 4 waves x 16 label-lanes, 64 labels per pass
  const int wid = tid >> 6, wl = tid & 63;
  for (int chb = 0; chb < nlab; chb += CROWS) {
    for (int i = tid; i < (CROWS * CNTW) / 2; i += 256) ((uint32_t*)u.cnt)[i] = 0u;
    __syncthreads();
    for (int p = tid; p < NPIX; p += 256) {
      if (lab[p]) {
        int dl = (int)labD[lab[p] - 1] - 1 - chb;   // active id or <0
        if (dl >= 0 && dl < CROWS) u.cnt[dl][p] = 1;
      }
    }
    __syncthreads();
    // pipelined run-cache serial replay (R7-proven semantics), per wave chunk
    if (wl < 16 && M > 0) {
      uint16_t* C = u.cnt[wid * 16 + wl];
      int lastRa = -1; unsigned lastVal = 0;
      int pfr = -1; unsigned pfv = 0;
      unsigned w = recW[0];
      int ra = (int)((w >> 11) & 1023u), rb = (int)(w >> 21);
      unsigned caL = C[ra], cbL = C[rb];
      for (int m = 0; m < M; ++m) {
        int mn = (m + 1 < M) ? m + 1 : m;
        unsigned wN = recW[mn];               // prefetch (stale set <= {lastRa, pfr})
        int raN = (int)((wN >> 11) & 1023u), rbN = (int)(wN >> 21);
        unsigned caN = C[raN], cbN = C[rbN];
        unsigned ca = (ra == lastRa) ? lastVal : ((ra == pfr) ? pfv : caL);
        unsigned cb = (rb == lastRa) ? lastVal : ((rb == pfr) ? pfv : cbL);
        int npfr = -1; unsigned npfv = 0;
        if (ra != lastRa) {
          if (lastRa >= 0) { C[lastRa] = (uint16_t)lastVal; npfr = lastRa; npfv = lastVal; }
          lastRa = ra; lastVal = ca;
        }
        if (cb) {
          if (lastVal) atomicAdd(&same[m], lastVal * cb);
          lastVal += cb;
        }
        pfr = npfr; pfv = npfv;
        ra = raN; rb = rbN; caL = caN; cbL = cbN;
      }
    }
    __syncthreads();
  }

  // ---- normalization sum S and masked loss contribution
  unsigned mys = 0u;
  for (int m = tid; m < M; m += 256)
    mys += sign ? same[m] : (totp[m] - same[m]);
  atomicAdd(&Ssum, mys);
  __syncthreads();
  const unsigned S = Ssum;

  double part = 0.0;
  if (S > 0u) {
    for (int m = tid; m < M; m += 256) {
      unsigned np = sign ? same[m] : (totp[m] - same[m]);
      if (np == 0u) continue;
      int e = (int)(recW[m] & 2047u);
      int a, b; edge_nodes(e, a, b);
      int cls = (lab[a] ? 0 : 1) + (lab[b] ? 0 : 1);
      bool keep = sign ? (cls != 0)    // ewp[gt<20]=0 -> keep cls 1,2
                       : (cls == 0);   // ewn[gt>=10]=0 -> keep cls 0
      if (!keep) continue;
      double fa, fb;
      if (sign) {
        double da = 20.0 - (double)Pw[a], db = 20.0 - (double)Pw[b];
        fa = da * da; fb = db * db;
      } else {
        fa = (double)Pw[a] * (double)Pw[a];
        fb = (double)Pw[b] * (double)Pw[b];
      }
      part += (double)np * (fa + fb);
    }
  }
  u.red[tid] = part;     // cnt region dead (replay loop ended with barrier)
  __syncthreads();
  for (int st = 128; st > 0; st >>= 1) {
    if (tid < st) u.red[tid] += u.red[tid + st];
    __syncthreads();
  }
  if (tid == 0) partG[t] = (S > 0u) ? (u.red[0] / (double)S) : 0.0;
}

__global__ __launch_bounds__(256) void final_reduce(
    const double* __restrict__ part, float* __restrict__ out)
{
  __shared__ double r[256];
  int tdx = threadIdx.x;
  r[tdx] = part[tdx];
  __syncthreads();
  for (int st = 128; st > 0; st >>= 1) {
    if (tdx < st) r[tdx] += r[tdx + st];
    __syncthreads();
  }
  if (tdx == 0) out[0] = (float)r[0];
}

extern "C" void kernel_launch(void* const* d_in, const int* in_sizes, int n_in,
                              void* d_out, int out_size, void* d_ws, size_t ws_size,
                              hipStream_t stream) {
  const float* y_true = (const float*)d_in[0];
  const float* y_pred = (const float*)d_in[1];
  char* ws = (char*)d_ws;
  k1_prep<<<128, 256, 0, stream>>>(y_true, y_pred, ws);
  k2_fused<<<256, 256, 0, stream>>>(ws);
  final_reduce<<<1, 256, 0, stream>>>((const double*)(ws + WS_PART), (float*)d_out);
}

// Round 9
// 563.305 us; speedup vs baseline: 1.1800x; 1.1800x over previous
//
#include <hip/hip_runtime.h>
#include <stdint.h>

#define NPIX 1024
#define NEDGE 1984
#define NSORT 2048
#define CROWS 64          // replay label rows (4 waves x 16)
#define CNTW (NPIX + 2)   // pad rows: replay lanes hit distinct banks

// ---- d_ws layout (~1.05 MB) ----
#define WS_PART   0u          // f64[256]   per-task loss partials
#define WS_SKIP   2048u       // u32[64]    per-window skip flag
#define WS_NLAB   2304u       // u32[128]   per (bat,win) active-label count
#define WS_PW     4096u       // f32[128*1024]
#define WS_LAB    528384u     // u16[128*1024]  CC labels (min-pixel-id+1, 0=bg)
#define WS_LABD   790528u     // u16[128*1024]  active dense id+1 at min pixel

__device__ __forceinline__ void edge_nodes(int e, int& a, int& b) {
  if (e < 992) { int r = e / 31; int c = e - r * 31; a = (r << 5) + c; b = a + 1; }
  else         { a = e - 992; b = a + 32; }
}

// ============ K1: load + skip predicate + 8-conn CC + label census ============
__global__ __launch_bounds__(256) void k1_prep(const float* __restrict__ y_true,
                                               const float* __restrict__ y_pred,
                                               char* __restrict__ ws) {
  __shared__ float    Pw[NPIX];
  __shared__ uint16_t lab[NPIX];
  __shared__ uint8_t  maskv[NPIX];
  __shared__ uint32_t lcnt[NPIX];
  __shared__ unsigned minP, maxP, minT, maxT;
  __shared__ int nl, changed;
  const int tid = threadIdx.x, pw = blockIdx.x, bat = pw >> 6, win = pw & 63;
  const int wr = win >> 3, wc = win & 7;
  if (tid == 0) { minP = ~0u; maxP = 0u; minT = ~0u; maxT = 0u; nl = 0; }
  __syncthreads();
  {
    unsigned mnP = ~0u, mxP = 0u, mnT = ~0u, mxT = 0u;
    for (int i = tid; i < 2 * NPIX; i += 256) {
      int bb = i >> 10, p = i & (NPIX - 1);
      int r = p >> 5, c = p & 31;
      size_t g = ((size_t)(bb * 256 + wr * 32 + r)) * 256 + (size_t)(wc * 32 + c);
      float pv = y_pred[g], tv = y_true[g];
      unsigned pu = __float_as_uint(pv), tu = __float_as_uint(tv);
      mnP = min(mnP, pu); mxP = max(mxP, pu);
      mnT = min(mnT, tu); mxT = max(mxT, tu);
      if (bb == bat) {
        Pw[p] = pv; maskv[p] = (tv == 0.f) ? 1 : 0;
        lab[p] = (tv == 0.f) ? (uint16_t)(p + 1) : (uint16_t)0;
        lcnt[p] = 0u;
      }
    }
    atomicMin(&minP, mnP); atomicMax(&maxP, mxP);   // valid: values >= 0
    atomicMin(&minT, mnT); atomicMax(&maxT, mxT);
  }
  __syncthreads();
  {
    float a = __uint_as_float(minP), b = __uint_as_float(maxP);
    float c2 = __uint_as_float(minT), d = __uint_as_float(maxT);
    int skip = (a == 1.f || b == 0.f || c2 == 1.f || d == 0.f) ? 1 : 0;
    if (tid == 0) ((uint32_t*)(ws + WS_SKIP))[win] = (uint32_t)skip;  // dup write: same value
    if (skip) return;
  }
  for (;;) {
    if (tid == 0) changed = 0;
    __syncthreads();
    for (int p = tid; p < NPIX; p += 256) {
      if (!maskv[p]) continue;
      int r = p >> 5, c = p & 31;
      unsigned m = lab[p];
      bool up = r > 0, dn = r < 31, lf = c > 0, rt = c < 31;
      if (up) {
        if (maskv[p-32])       { unsigned v = lab[p-32]; if (v < m) m = v; }
        if (lf && maskv[p-33]) { unsigned v = lab[p-33]; if (v < m) m = v; }
        if (rt && maskv[p-31]) { unsigned v = lab[p-31]; if (v < m) m = v; }
      }
      if (dn) {
        if (maskv[p+32])       { unsigned v = lab[p+32]; if (v < m) m = v; }
        if (lf && maskv[p+31]) { unsigned v = lab[p+31]; if (v < m) m = v; }
        if (rt && maskv[p+33]) { unsigned v = lab[p+33]; if (v < m) m = v; }
      }
      if (lf && maskv[p-1]) { unsigned v = lab[p-1]; if (v < m) m = v; }
      if (rt && maskv[p+1]) { unsigned v = lab[p+1]; if (v < m) m = v; }
      unsigned m2 = lab[m - 1]; if (m2 && m2 < m) m = m2;
      m2 = lab[m - 1];          if (m2 && m2 < m) m = m2;
      if (m < (unsigned)lab[p]) { lab[p] = (uint16_t)m; changed = 1; }
    }
    __syncthreads();
    int ch = changed;
    __syncthreads();
    if (!ch) break;
  }
  for (int p = tid; p < NPIX; p += 256)
    if (maskv[p]) atomicAdd(&lcnt[lab[p] - 1], 1u);
  __syncthreads();
  uint16_t* labDG = (uint16_t*)(ws + WS_LABD) + (size_t)pw * NPIX;
  for (int p = tid; p < NPIX; p += 256) {
    uint16_t v = 0;
    if (maskv[p] && lab[p] == (uint16_t)(p + 1) && lcnt[p] >= 2u)
      v = (uint16_t)(atomicAdd(&nl, 1) + 1);
    labDG[p] = v;
  }
  __syncthreads();
  float*    PwG  = (float*)(ws + WS_PW)  + (size_t)pw * NPIX;
  uint16_t* labG = (uint16_t*)(ws + WS_LAB) + (size_t)pw * NPIX;
  for (int p = tid; p < NPIX; p += 256) { PwG[p] = Pw[p]; labG[p] = lab[p]; }
  if (tid == 0) ((uint32_t*)(ws + WS_NLAB))[pw] = (uint32_t)nl;
}

// ============ K2: fused sort + sizeless Kruskal + replay(+totprod) + epilogue ============
__global__ __launch_bounds__(256) void k2_fused(char* __restrict__ ws) {
  __shared__ union {
    struct {
      unsigned long long keys[NSORT];   // 16384 B (sort + kruskal edge order)
      uint16_t par[NPIX];               //  2048 B
    } kp;
    uint16_t cnt[CROWS][CNTW];          // 131328 B (replay)
    double   red[256];                  //   2048 B (final reduction)
  } u;
  __shared__ float    Pw[NPIX];
  __shared__ uint16_t lab[NPIX];
  __shared__ uint16_t labD[NPIX];
  __shared__ uint32_t recW[NPIX];
  __shared__ uint32_t totp[NPIX];
  __shared__ uint32_t same[NPIX];
  __shared__ unsigned Ssum;
  __shared__ int Msh;
  const int tid = threadIdx.x, t = blockIdx.x;
  const int sign = t & 1, win = (t >> 1) & 63, bat = t >> 7;
  const int pw = bat * 64 + win;
  double* partG = (double*)(ws + WS_PART);
  if (((const uint32_t*)(ws + WS_SKIP))[win]) { if (tid == 0) partG[t] = 0.0; return; }
  const int nlab = (int)((const uint32_t*)(ws + WS_NLAB))[pw];
  if (tid == 0) { Ssum = 0u; Msh = 0; }
  {
    const float*    PwG   = (const float*)(ws + WS_PW)   + (size_t)pw * NPIX;
    const uint16_t* labG  = (const uint16_t*)(ws + WS_LAB)  + (size_t)pw * NPIX;
    const uint16_t* labDG = (const uint16_t*)(ws + WS_LABD) + (size_t)pw * NPIX;
    for (int p = tid; p < NPIX; p += 256) {
      Pw[p] = PwG[p]; lab[p] = labG[p]; labD[p] = labDG[p];
      u.kp.par[p] = (uint16_t)p;
      same[p] = 0u; totp[p] = 0u;
    }
  }
  __syncthreads();
  // ---- edge keys (cost desc, index asc -> pack (~bits(cost), e), sort asc)
  for (int e = tid; e < NSORT; e += 256) {
    if (e < NEDGE) {
      int a, b; edge_nodes(e, a, b);
      int cls = (lab[a] ? 0 : 1) + (lab[b] ? 0 : 1);
      float cost = Pw[a] + Pw[b];
      if (sign == 0) { if (cls == 2) cost = 20.0f; }   // costs_n[gt>20]=20
      else           { if (cls == 0) cost = 0.0f;  }   // costs_p[gt<10]=0
      u.kp.keys[e] = (((unsigned long long)(__float_as_uint(cost) ^ 0xFFFFFFFFu)) << 32)
                     | (unsigned long long)(unsigned)e;
    } else u.kp.keys[e] = ~0ull;
  }
  __syncthreads();
  // ---- register-fused bitonic sort (proven R7/R8)
  {
    unsigned long long x[8];
    const int baseI = tid * 8;
    #pragma unroll
    for (int v = 0; v < 8; ++v) x[v] = u.kp.keys[baseI + v];
    #pragma unroll
    for (int kk = 2; kk <= 8; kk <<= 1) {
      #pragma unroll
      for (int j = kk >> 1; j > 0; j >>= 1) {
        #pragma unroll
        for (int v = 0; v < 8; ++v) {
          int p = v ^ j;
          if (p > v) {
            bool asc = (((baseI + v) & kk) == 0);
            unsigned long long A = x[v], B = x[p];
            if ((A > B) == asc) { x[v] = B; x[p] = A; }
          }
        }
      }
    }
    #pragma unroll
    for (int v = 0; v < 8; ++v) u.kp.keys[baseI + v] = x[v];
  }
  for (int k = 16; k <= NSORT; k <<= 1) {
    for (int j = k >> 1; j >= 8; j >>= 1) {
      __syncthreads();
      for (int q = tid; q < NSORT / 2; q += 256) {
        int i = ((q & ~(j - 1)) << 1) | (q & (j - 1));
        int p = i + j;
        bool asc = ((i & k) == 0);
        unsigned long long A = u.kp.keys[i], B = u.kp.keys[p];
        if ((A > B) == asc) { u.kp.keys[i] = B; u.kp.keys[p] = A; }
      }
    }
    __syncthreads();
    {
      unsigned long long x[8];
      const int baseI = tid * 8;
      const bool asc = ((baseI & k) == 0);
      #pragma unroll
      for (int v = 0; v < 8; ++v) x[v] = u.kp.keys[baseI + v];
      #pragma unroll
      for (int j = 4; j > 0; j >>= 1) {
        #pragma unroll
        for (int v = 0; v < 8; ++v) {
          int p = v ^ j;
          if (p > v) {
            unsigned long long A = x[v], B = x[p];
            if ((A > B) == asc) { x[v] = B; x[p] = A; }
          }
        }
      }
      #pragma unroll
      for (int v = 0; v < 8; ++v) u.kp.keys[baseI + v] = x[v];
    }
  }
  __syncthreads();
  // ---- sizeless wave-cooperative Kruskal (wave 0); ALL writes deferred to
  // end-of-batch parallel stores. Emits EVERY merge (records with no labeled
  // nodes yield same=totp=0 downstream -> harmless). Sizes/totprod move to
  // the replay pseudo-row. All ballots/readlanes in uniform control flow.
  if (tid < 64) {
    const int lane = tid;
    int mTotal = 0;
    for (int base = 0; base < NEDGE; base += 64) {
      unsigned e = (unsigned)u.kp.keys[base + lane];
      int a, b; edge_nodes((int)e, a, b);
      int xa = a, xb = b;
      for (;;) {
        int pa = u.kp.par[xa], pb = u.kp.par[xb];   // read-only dual walk
        if (pa == xa && pb == xb) break;
        xa = pa; xb = pb;
      }
      bool cand = (xa != xb);
      unsigned long long cm = __ballot(cand);
      unsigned w0 = (unsigned)xa | ((unsigned)xb << 10) | (e << 20);

      int mb = 0;
      int mFrom = -1, mToCur = -1, recA = 0; unsigned recE = 0;
      while (cm) {
        int i = __ffsll((long long)cm) - 1;
        cm &= cm - 1;
        unsigned W0 = (unsigned)__builtin_amdgcn_readlane((int)w0, i);
        int rA = (int)(W0 & 1023u);
        int rB = (int)((W0 >> 10) & 1023u);
        unsigned eI = W0 >> 20;
        // O(1) rename via always-current mToCur invariant (mFrom unique)
        unsigned long long mmA = __ballot(mFrom == rA);
        unsigned long long mmB = __ballot(mFrom == rB);
        int vA = __builtin_amdgcn_readlane(mToCur, (__ffsll((long long)mmA) - 1) & 63);
        int vB = __builtin_amdgcn_readlane(mToCur, (__ffsll((long long)mmB) - 1) & 63);
        rA = mmA ? vA : rA;
        rB = mmB ? vB : rB;
        if (rA != rB) {                      // uniform branch
          if (lane == mb) { mFrom = rB; mToCur = rA; recA = rA; recE = eI; }
          mToCur = (mToCur == rB) ? rA : mToCur;   // keep invariant
          ++mb;
        }
      }
      // end-of-batch deferred writes (parallel, off the serial chain)
      if (lane < mb) {
        u.kp.par[mFrom] = (uint16_t)recA;    // reference orientation par[rB]=rA
        recW[mTotal + lane] = recE | ((unsigned)recA << 11) | ((unsigned)mFrom << 21);
      }
      mTotal += mb;
      // batched pointer-jump compression (1 write/node, conflict-free)
      if (mb && (base + 64 < NEDGE)) {
        for (int pass = 0; pass < 2; ++pass) {
          uint16_t vv[16];
          #pragma unroll
          for (int j = 0; j < 16; ++j) vv[j] = u.kp.par[j * 64 + lane];
          #pragma unroll
          for (int j = 0; j < 16; ++j) vv[j] = u.kp.par[vv[j]];
          #pragma unroll
          for (int j = 0; j < 16; ++j) u.kp.par[j * 64 + lane] = vv[j];
        }
      }
    }
    if (lane == 0) Msh = mTotal;
  }
  __syncthreads();
  const int M = Msh;

  // ---- replay: 4 waves x 16 label-lanes; row nlab = pseudo-row (ALL labeled
  // pixels) whose ca*cb per record IS totprod (sA*sB of labeled nodes).
  const int wid = tid >> 6, wl = tid & 63;
  const int nRows = nlab + 1;
  for (int chb = 0; chb < nRows; chb += CROWS) {
    for (int i = tid; i < (CROWS * CNTW) / 2; i += 256) ((uint32_t*)u.cnt)[i] = 0u;
    __syncthreads();
    {
      int dp = nlab - chb;
      for (int p = tid; p < NPIX; p += 256) {
        if (lab[p]) {
          int dl = (int)labD[lab[p] - 1] - 1 - chb;   // active id or <0
          if (dl >= 0 && dl < CROWS) u.cnt[dl][p] = 1;
          if (dp >= 0 && dp < CROWS) u.cnt[dp][p] = 1; // pseudo row
        }
      }
    }
    __syncthreads();
    // pipelined run-cache serial replay (R7-proven semantics)
    if (wl < 16 && M > 0) {
      int myRow = chb + wid * 16 + wl;
      if (myRow < nRows) {
        const bool isP = (myRow == nlab);
        uint16_t* C = u.cnt[wid * 16 + wl];
        int lastRa = -1; unsigned lastVal = 0;
        int pfr = -1; unsigned pfv = 0;
        unsigned w = recW[0];
        int ra = (int)((w >> 11) & 1023u), rb = (int)(w >> 21);
        unsigned caL = C[ra], cbL = C[rb];
        for (int m = 0; m < M; ++m) {
          int mn = (m + 1 < M) ? m + 1 : m;
          unsigned wN = recW[mn];               // prefetch (stale set <= {lastRa, pfr})
          int raN = (int)((wN >> 11) & 1023u), rbN = (int)(wN >> 21);
          unsigned caN = C[raN], cbN = C[rbN];
          unsigned ca = (ra == lastRa) ? lastVal : ((ra == pfr) ? pfv : caL);
          unsigned cb = (rb == lastRa) ? lastVal : ((rb == pfr) ? pfv : cbL);
          int npfr = -1; unsigned npfv = 0;
          if (ra != lastRa) {
            if (lastRa >= 0) { C[lastRa] = (uint16_t)lastVal; npfr = lastRa; npfv = lastVal; }
            lastRa = ra; lastVal = ca;
          }
          if (cb) {
            if (isP) totp[m] = lastVal * cb;    // single writer, plain store
            else if (lastVal) atomicAdd(&same[m], lastVal * cb);
            lastVal += cb;
          }
          pfr = npfr; pfv = npfv;
          ra = raN; rb = rbN; caL = caN; cbL = cbN;
        }
      }
    }
    __syncthreads();
  }

  // ---- normalization sum S and masked loss contribution
  unsigned mys = 0u;
  for (int m = tid; m < M; m += 256)
    mys += sign ? same[m] : (totp[m] - same[m]);
  atomicAdd(&Ssum, mys);
  __syncthreads();
  const unsigned S = Ssum;

  double part = 0.0;
  if (S > 0u) {
    for (int m = tid; m < M; m += 256) {
      unsigned np = sign ? same[m] : (totp[m] - same[m]);
      if (np == 0u) continue;
      int e = (int)(recW[m] & 2047u);
      int a, b; edge_nodes(e, a, b);
      int cls = (lab[a] ? 0 : 1) + (lab[b] ? 0 : 1);
      bool keep = sign ? (cls != 0)    // ewp[gt<20]=0 -> keep cls 1,2
                       : (cls == 0);   // ewn[gt>=10]=0 -> keep cls 0
      if (!keep) continue;
      double fa, fb;
      if (sign) {
        double da = 20.0 - (double)Pw[a], db = 20.0 - (double)Pw[b];
        fa = da * da; fb = db * db;
      } else {
        fa = (double)Pw[a] * (double)Pw[a];
        fb = (double)Pw[b] * (double)Pw[b];
      }
      part += (double)np * (fa + fb);
    }
  }
  u.red[tid] = part;     // cnt region dead (replay loop ended with barrier)
  __syncthreads();
  for (int st = 128; st > 0; st >>= 1) {
    if (tid < st) u.red[tid] += u.red[tid + st];
    __syncthreads();
  }
  if (tid == 0) partG[t] = (S > 0u) ? (u.red[0] / (double)S) : 0.0;
}

__global__ __launch_bounds__(256) void final_reduce(
    const double* __restrict__ part, float* __restrict__ out)
{
  __shared__ double r[256];
  int tdx = threadIdx.x;
  r[tdx] = part[tdx];
  __syncthreads();
  for (int st = 128; st > 0; st >>= 1) {
    if (tdx < st) r[tdx] += r[tdx + st];
    __syncthreads();
  }
  if (tdx == 0) out[0] = (float)r[0];
}

extern "C" void kernel_launch(void* const* d_in, const int* in_sizes, int n_in,
                              void* d_out, int out_size, void* d_ws, size_t ws_size,
                              hipStream_t stream) {
  const float* y_true = (const float*)d_in[0];
  const float* y_pred = (const float*)d_in[1];
  char* ws = (char*)d_ws;
  k1_prep<<<128, 256, 0, stream>>>(y_true, y_pred, ws);
  k2_fused<<<256, 256, 0, stream>>>(ws);
  final_reduce<<<1, 256, 0, stream>>>((const double*)(ws + WS_PART), (float*)d_out);
}

// Round 10
// 507.590 us; speedup vs baseline: 1.3095x; 1.1098x over previous
//
#include <hip/hip_runtime.h>
#include <stdint.h>

#define NPIX 1024
#define NEDGE 1984
#define NSORT 2048
#define CROWS 64          // replay label rows (4 waves x 16)
#define CNTW (NPIX + 2)   // pad rows: replay lanes hit distinct banks

// ---- d_ws layout (~1.05 MB) ----
#define WS_PART   0u          // f64[256]   per-task loss partials
#define WS_SKIP   2048u       // u32[64]    per-window skip flag
#define WS_NLAB   2304u       // u32[128]   per (bat,win) active-label count
#define WS_PW     4096u       // f32[128*1024]
#define WS_LAB    528384u     // u16[128*1024]  CC labels (min-pixel-id+1, 0=bg)
#define WS_LABD   790528u     // u16[128*1024]  active dense id+1 at min pixel

__device__ __forceinline__ void edge_nodes(int e, int& a, int& b) {
  if (e < 992) { int r = e / 31; int c = e - r * 31; a = (r << 5) + c; b = a + 1; }
  else         { a = e - 992; b = a + 32; }
}

// ============ K1: load + skip predicate + 8-conn CC + label census ============
__global__ __launch_bounds__(256) void k1_prep(const float* __restrict__ y_true,
                                               const float* __restrict__ y_pred,
                                               char* __restrict__ ws) {
  __shared__ float    Pw[NPIX];
  __shared__ uint16_t lab[NPIX];
  __shared__ uint8_t  maskv[NPIX];
  __shared__ uint32_t lcnt[NPIX];
  __shared__ unsigned minP, maxP, minT, maxT;
  __shared__ int nl, changed;
  const int tid = threadIdx.x, pw = blockIdx.x, bat = pw >> 6, win = pw & 63;
  const int wr = win >> 3, wc = win & 7;
  if (tid == 0) { minP = ~0u; maxP = 0u; minT = ~0u; maxT = 0u; nl = 0; }
  __syncthreads();
  {
    unsigned mnP = ~0u, mxP = 0u, mnT = ~0u, mxT = 0u;
    for (int i = tid; i < 2 * NPIX; i += 256) {
      int bb = i >> 10, p = i & (NPIX - 1);
      int r = p >> 5, c = p & 31;
      size_t g = ((size_t)(bb * 256 + wr * 32 + r)) * 256 + (size_t)(wc * 32 + c);
      float pv = y_pred[g], tv = y_true[g];
      unsigned pu = __float_as_uint(pv), tu = __float_as_uint(tv);
      mnP = min(mnP, pu); mxP = max(mxP, pu);
      mnT = min(mnT, tu); mxT = max(mxT, tu);
      if (bb == bat) {
        Pw[p] = pv; maskv[p] = (tv == 0.f) ? 1 : 0;
        lab[p] = (tv == 0.f) ? (uint16_t)(p + 1) : (uint16_t)0;
        lcnt[p] = 0u;
      }
    }
    atomicMin(&minP, mnP); atomicMax(&maxP, mxP);   // valid: values >= 0
    atomicMin(&minT, mnT); atomicMax(&maxT, mxT);
  }
  __syncthreads();
  {
    float a = __uint_as_float(minP), b = __uint_as_float(maxP);
    float c2 = __uint_as_float(minT), d = __uint_as_float(maxT);
    int skip = (a == 1.f || b == 0.f || c2 == 1.f || d == 0.f) ? 1 : 0;
    if (tid == 0) ((uint32_t*)(ws + WS_SKIP))[win] = (uint32_t)skip;  // dup write: same value
    if (skip) return;
  }
  for (;;) {
    if (tid == 0) changed = 0;
    __syncthreads();
    for (int p = tid; p < NPIX; p += 256) {
      if (!maskv[p]) continue;
      int r = p >> 5, c = p & 31;
      unsigned m = lab[p];
      bool up = r > 0, dn = r < 31, lf = c > 0, rt = c < 31;
      if (up) {
        if (maskv[p-32])       { unsigned v = lab[p-32]; if (v < m) m = v; }
        if (lf && maskv[p-33]) { unsigned v = lab[p-33]; if (v < m) m = v; }
        if (rt && maskv[p-31]) { unsigned v = lab[p-31]; if (v < m) m = v; }
      }
      if (dn) {
        if (maskv[p+32])       { unsigned v = lab[p+32]; if (v < m) m = v; }
        if (lf && maskv[p+31]) { unsigned v = lab[p+31]; if (v < m) m = v; }
        if (rt && maskv[p+33]) { unsigned v = lab[p+33]; if (v < m) m = v; }
      }
      if (lf && maskv[p-1]) { unsigned v = lab[p-1]; if (v < m) m = v; }
      if (rt && maskv[p+1]) { unsigned v = lab[p+1]; if (v < m) m = v; }
      unsigned m2 = lab[m - 1]; if (m2 && m2 < m) m = m2;
      m2 = lab[m - 1];          if (m2 && m2 < m) m = m2;
      if (m < (unsigned)lab[p]) { lab[p] = (uint16_t)m; changed = 1; }
    }
    __syncthreads();
    int ch = changed;
    __syncthreads();
    if (!ch) break;
  }
  for (int p = tid; p < NPIX; p += 256)
    if (maskv[p]) atomicAdd(&lcnt[lab[p] - 1], 1u);
  __syncthreads();
  uint16_t* labDG = (uint16_t*)(ws + WS_LABD) + (size_t)pw * NPIX;
  for (int p = tid; p < NPIX; p += 256) {
    uint16_t v = 0;
    if (maskv[p] && lab[p] == (uint16_t)(p + 1) && lcnt[p] >= 2u)
      v = (uint16_t)(atomicAdd(&nl, 1) + 1);
    labDG[p] = v;
  }
  __syncthreads();
  float*    PwG  = (float*)(ws + WS_PW)  + (size_t)pw * NPIX;
  uint16_t* labG = (uint16_t*)(ws + WS_LAB) + (size_t)pw * NPIX;
  for (int p = tid; p < NPIX; p += 256) { PwG[p] = Pw[p]; labG[p] = lab[p]; }
  if (tid == 0) ((uint32_t*)(ws + WS_NLAB))[pw] = (uint32_t)nl;
}

// ============ K2: fused sort + register-UF Kruskal + replay(+totprod) + epilogue ============
__global__ __launch_bounds__(256) void k2_fused(char* __restrict__ ws) {
  __shared__ union {
    struct {
      unsigned long long keys[NSORT];   // 16384 B (sort + kruskal edge order)
      uint16_t par[NPIX];               //  2048 B
    } kp;
    uint16_t cnt[CROWS][CNTW];          // 131328 B (replay)
    double   red[256];                  //   2048 B (final reduction)
  } u;
  __shared__ float    Pw[NPIX];
  __shared__ uint16_t lab[NPIX];
  __shared__ uint16_t labD[NPIX];
  __shared__ uint32_t recW[NPIX];
  __shared__ uint32_t totp[NPIX];
  __shared__ uint32_t same[NPIX];
  __shared__ unsigned Ssum;
  __shared__ int Msh;
  const int tid = threadIdx.x, t = blockIdx.x;
  const int sign = t & 1, win = (t >> 1) & 63, bat = t >> 7;
  const int pw = bat * 64 + win;
  double* partG = (double*)(ws + WS_PART);
  if (((const uint32_t*)(ws + WS_SKIP))[win]) { if (tid == 0) partG[t] = 0.0; return; }
  const int nlab = (int)((const uint32_t*)(ws + WS_NLAB))[pw];
  if (tid == 0) { Ssum = 0u; Msh = 0; }
  {
    const float*    PwG   = (const float*)(ws + WS_PW)   + (size_t)pw * NPIX;
    const uint16_t* labG  = (const uint16_t*)(ws + WS_LAB)  + (size_t)pw * NPIX;
    const uint16_t* labDG = (const uint16_t*)(ws + WS_LABD) + (size_t)pw * NPIX;
    for (int p = tid; p < NPIX; p += 256) {
      Pw[p] = PwG[p]; lab[p] = labG[p]; labD[p] = labDG[p];
      u.kp.par[p] = (uint16_t)p;
      same[p] = 0u; totp[p] = 0u;
    }
  }
  __syncthreads();
  // ---- edge keys (cost desc, index asc -> pack (~bits(cost), e), sort asc)
  for (int e = tid; e < NSORT; e += 256) {
    if (e < NEDGE) {
      int a, b; edge_nodes(e, a, b);
      int cls = (lab[a] ? 0 : 1) + (lab[b] ? 0 : 1);
      float cost = Pw[a] + Pw[b];
      if (sign == 0) { if (cls == 2) cost = 20.0f; }   // costs_n[gt>20]=20
      else           { if (cls == 0) cost = 0.0f;  }   // costs_p[gt<10]=0
      u.kp.keys[e] = (((unsigned long long)(__float_as_uint(cost) ^ 0xFFFFFFFFu)) << 32)
                     | (unsigned long long)(unsigned)e;
    } else u.kp.keys[e] = ~0ull;
  }
  __syncthreads();
  // ---- register-fused bitonic sort (proven R7-R9)
  {
    unsigned long long x[8];
    const int baseI = tid * 8;
    #pragma unroll
    for (int v = 0; v < 8; ++v) x[v] = u.kp.keys[baseI + v];
    #pragma unroll
    for (int kk = 2; kk <= 8; kk <<= 1) {
      #pragma unroll
      for (int j = kk >> 1; j > 0; j >>= 1) {
        #pragma unroll
        for (int v = 0; v < 8; ++v) {
          int p = v ^ j;
          if (p > v) {
            bool asc = (((baseI + v) & kk) == 0);
            unsigned long long A = x[v], B = x[p];
            if ((A > B) == asc) { x[v] = B; x[p] = A; }
          }
        }
      }
    }
    #pragma unroll
    for (int v = 0; v < 8; ++v) u.kp.keys[baseI + v] = x[v];
  }
  for (int k = 16; k <= NSORT; k <<= 1) {
    for (int j = k >> 1; j >= 8; j >>= 1) {
      __syncthreads();
      for (int q = tid; q < NSORT / 2; q += 256) {
        int i = ((q & ~(j - 1)) << 1) | (q & (j - 1));
        int p = i + j;
        bool asc = ((i & k) == 0);
        unsigned long long A = u.kp.keys[i], B = u.kp.keys[p];
        if ((A > B) == asc) { u.kp.keys[i] = B; u.kp.keys[p] = A; }
      }
    }
    __syncthreads();
    {
      unsigned long long x[8];
      const int baseI = tid * 8;
      const bool asc = ((baseI & k) == 0);
      #pragma unroll
      for (int v = 0; v < 8; ++v) x[v] = u.kp.keys[baseI + v];
      #pragma unroll
      for (int j = 4; j > 0; j >>= 1) {
        #pragma unroll
        for (int v = 0; v < 8; ++v) {
          int p = v ^ j;
          if (p > v) {
            unsigned long long A = x[v], B = x[p];
            if ((A > B) == asc) { x[v] = B; x[p] = A; }
          }
        }
      }
      #pragma unroll
      for (int v = 0; v < 8; ++v) u.kp.keys[baseI + v] = x[v];
    }
  }
  __syncthreads();
  // ---- wave-cooperative Kruskal (wave 0) with ALWAYS-CURRENT per-lane (ra,rb):
  // on each merge rB->rA (SGPRs via readlane), every lane renames its own
  // ra/rb registers -> consume = ff1 + 2 readlane + SCALAR compare. No ballots,
  // no slot-table renames in the serial loop. Writes deferred to end-of-batch.
  // All cross-lane ops in wave-uniform control flow (CDNA exec-mask rule).
  if (tid < 64) {
    const int lane = tid;
    int mTotal = 0;
    for (int base = 0; base < NEDGE; base += 64) {
      unsigned e = (unsigned)u.kp.keys[base + lane];
      int a, b; edge_nodes((int)e, a, b);
      int xa = a, xb = b;
      for (;;) {
        int pa = u.kp.par[xa], pb = u.kp.par[xb];   // read-only dual walk
        if (pa == xa && pb == xb) break;
        xa = pa; xb = pb;
      }
      int ra = xa, rb = xb;
      unsigned long long cm = __ballot(ra != rb);
      int mb = 0;
      unsigned recP = 0;                    // lane-mb packed record
      while (cm) {
        int i = __ffsll((long long)cm) - 1;
        cm &= cm - 1;
        int rA = __builtin_amdgcn_readlane(ra, i);   // SGPR (current root of a_i)
        int rB = __builtin_amdgcn_readlane(rb, i);   // SGPR (current root of b_i)
        if (rA != rB) {                               // scalar branch
          unsigned eI = (unsigned)__builtin_amdgcn_readlane((int)e, i);
          unsigned pk = eI | ((unsigned)rA << 11) | ((unsigned)rB << 21);
          if (lane == mb) recP = pk;                  // park record in lane mb
          ra = (ra == rB) ? rA : ra;                  // union-find in registers
          rb = (rb == rB) ? rA : rb;
          ++mb;
        }
      }
      // end-of-batch deferred writes (parallel, off the serial chain)
      if (lane < mb) {
        int rAo = (int)((recP >> 11) & 1023u);
        int rBo = (int)(recP >> 21);
        u.kp.par[rBo] = (uint16_t)rAo;      // reference orientation par[rB]=rA
        recW[mTotal + lane] = recP;
      }
      mTotal += mb;
      // batched pointer-jump compression (1 write/node, conflict-free)
      if (mb && (base + 64 < NEDGE)) {
        for (int pass = 0; pass < 2; ++pass) {
          uint16_t vv[16];
          #pragma unroll
          for (int j = 0; j < 16; ++j) vv[j] = u.kp.par[j * 64 + lane];
          #pragma unroll
          for (int j = 0; j < 16; ++j) vv[j] = u.kp.par[vv[j]];
          #pragma unroll
          for (int j = 0; j < 16; ++j) u.kp.par[j * 64 + lane] = vv[j];
        }
      }
    }
    if (lane == 0) Msh = mTotal;
  }
  __syncthreads();
  const int M = Msh;

  // ---- replay: 4 waves x 16 label-lanes; row nlab = pseudo-row (ALL labeled
  // pixels) whose ca*cb per record IS totprod (sA*sB of labeled nodes).
  const int wid = tid >> 6, wl = tid & 63;
  const int nRows = nlab + 1;
  for (int chb = 0; chb < nRows; chb += CROWS) {
    for (int i = tid; i < (CROWS * CNTW) / 2; i += 256) ((uint32_t*)u.cnt)[i] = 0u;
    __syncthreads();
    {
      int dp = nlab - chb;
      for (int p = tid; p < NPIX; p += 256) {
        if (lab[p]) {
          int dl = (int)labD[lab[p] - 1] - 1 - chb;   // active id or <0
          if (dl >= 0 && dl < CROWS) u.cnt[dl][p] = 1;
          if (dp >= 0 && dp < CROWS) u.cnt[dp][p] = 1; // pseudo row
        }
      }
    }
    __syncthreads();
    // pipelined run-cache serial replay (R7-proven semantics)
    if (wl < 16 && M > 0) {
      int myRow = chb + wid * 16 + wl;
      if (myRow < nRows) {
        const bool isP = (myRow == nlab);
        uint16_t* C = u.cnt[wid * 16 + wl];
        int lastRa = -1; unsigned lastVal = 0;
        int pfr = -1; unsigned pfv = 0;
        unsigned w = recW[0];
        int ra = (int)((w >> 11) & 1023u), rb = (int)(w >> 21);
        unsigned caL = C[ra], cbL = C[rb];
        for (int m = 0; m < M; ++m) {
          int mn = (m + 1 < M) ? m + 1 : m;
          unsigned wN = recW[mn];               // prefetch (stale set <= {lastRa, pfr})
          int raN = (int)((wN >> 11) & 1023u), rbN = (int)(wN >> 21);
          unsigned caN = C[raN], cbN = C[rbN];
          unsigned ca = (ra == lastRa) ? lastVal : ((ra == pfr) ? pfv : caL);
          unsigned cb = (rb == lastRa) ? lastVal : ((rb == pfr) ? pfv : cbL);
          int npfr = -1; unsigned npfv = 0;
          if (ra != lastRa) {
            if (lastRa >= 0) { C[lastRa] = (uint16_t)lastVal; npfr = lastRa; npfv = lastVal; }
            lastRa = ra; lastVal = ca;
          }
          if (cb) {
            if (isP) totp[m] = lastVal * cb;    // single writer, plain store
            else if (lastVal) atomicAdd(&same[m], lastVal * cb);
            lastVal += cb;
          }
          pfr = npfr; pfv = npfv;
          ra = raN; rb = rbN; caL = caN; cbL = cbN;
        }
      }
    }
    __syncthreads();
  }

  // ---- normalization sum S and masked loss contribution
  unsigned mys = 0u;
  for (int m = tid; m < M; m += 256)
    mys += sign ? same[m] : (totp[m] - same[m]);
  atomicAdd(&Ssum, mys);
  __syncthreads();
  const unsigned S = Ssum;

  double part = 0.0;
  if (S > 0u) {
    for (int m = tid; m < M; m += 256) {
      unsigned np = sign ? same[m] : (totp[m] - same[m]);
      if (np == 0u) continue;
      int e = (int)(recW[m] & 2047u);
      int a, b; edge_nodes(e, a, b);
      int cls = (lab[a] ? 0 : 1) + (lab[b] ? 0 : 1);
      bool keep = sign ? (cls != 0)    // ewp[gt<20]=0 -> keep cls 1,2
                       : (cls == 0);   // ewn[gt>=10]=0 -> keep cls 0
      if (!keep) continue;
      double fa, fb;
      if (sign) {
        double da = 20.0 - (double)Pw[a], db = 20.0 - (double)Pw[b];
        fa = da * da; fb = db * db;
      } else {
        fa = (double)Pw[a] * (double)Pw[a];
        fb = (double)Pw[b] * (double)Pw[b];
      }
      part += (double)np * (fa + fb);
    }
  }
  u.red[tid] = part;     // cnt region dead (replay loop ended with barrier)
  __syncthreads();
  for (int st = 128; st > 0; st >>= 1) {
    if (tid < st) u.red[tid] += u.red[tid + st];
    __syncthreads();
  }
  if (tid == 0) partG[t] = (S > 0u) ? (u.red[0] / (double)S) : 0.0;
}

__global__ __launch_bounds__(256) void final_reduce(
    const double* __restrict__ part, float* __restrict__ out)
{
  __shared__ double r[256];
  int tdx = threadIdx.x;
  r[tdx] = part[tdx];
  __syncthreads();
  for (int st = 128; st > 0; st >>= 1) {
    if (tdx < st) r[tdx] += r[tdx + st];
    __syncthreads();
  }
  if (tdx == 0) out[0] = (float)r[0];
}

extern "C" void kernel_launch(void* const* d_in, const int* in_sizes, int n_in,
                              void* d_out, int out_size, void* d_ws, size_t ws_size,
                              hipStream_t stream) {
  const float* y_true = (const float*)d_in[0];
  const float* y_pred = (const float*)d_in[1];
  char* ws = (char*)d_ws;
  k1_prep<<<128, 256, 0, stream>>>(y_true, y_pred, ws);
  k2_fused<<<256, 256, 0, stream>>>(ws);
  final_reduce<<<1, 256, 0, stream>>>((const double*)(ws + WS_PART), (float*)d_out);
}